// Round 5
// baseline (238.951 us; speedup 1.0000x reference)
//
#include <hip/hip_runtime.h>
#include <hip/hip_bf16.h>

typedef short short8 __attribute__((ext_vector_type(8)));
typedef float float4v __attribute__((ext_vector_type(4)));

#define MFMA(a, b, c) __builtin_amdgcn_mfma_f32_16x16x32_bf16((a), (b), (c), 0, 0, 0)

typedef const __attribute__((address_space(1))) unsigned int gu32;
typedef __attribute__((address_space(3))) unsigned int lu32;
#define GLOAD_LDS16(g, l) __builtin_amdgcn_global_load_lds((gu32*)(g), (lu32*)(l), 16, 0, 0)

// counted vmem wait: keeps newest N loads in flight across the barrier
#define VMWAIT(n) asm volatile("s_waitcnt vmcnt(" n ")" ::: "memory")

#define LOG2E 1.4426950408889634f

static __device__ __forceinline__ unsigned short f2bf(float f) {
    union { float f; unsigned u; } v; v.f = f;
    unsigned r = (v.u + 0x7fffu + ((v.u >> 16) & 1u)) >> 16;
    return (unsigned short)r;
}
static __device__ __forceinline__ float bf2f(unsigned short h) {
    union { unsigned u; float f; } v; v.u = ((unsigned)h) << 16;
    return v.f;
}
// packed RNE fp32x2 -> bf16x2 (single v_cvt_pk on gfx950)
static __device__ __forceinline__ unsigned pk2bf(float a, float b) {
    union { __hip_bfloat162 h; unsigned u; } cv;
    cv.h = __float22bfloat162_rn(make_float2(a, b));
    return cv.u;
}

// Fragment-blocked layouts: each MFMA fragment (16 rows x 32 k) = 1024
// contiguous bytes; lane i's 16B piece at offset i*16.
static __device__ __forceinline__ int qk_idx(int b, int n, int o) {
    int frag = (b * 512 + (n >> 4)) * 2 + (o >> 5);
    return frag * 512 + ((o >> 3) & 3) * 128 + (n & 15) * 8 + (o & 7);
}
static __device__ __forceinline__ int v_idx(int b, int c, int n) {
    int frag = (b * 256 + (n >> 5)) * 16 + (c >> 4);
    return frag * 512 + ((n >> 3) & 3) * 128 + (c & 15) * 8 + (n & 7);
}

// ---------------------------------------------------------------------------
// Kernel 0: weights fp32 -> bf16 (hi for all; lo for Wq/Wk split path)
// ---------------------------------------------------------------------------
__global__ void wcvt(const float* __restrict__ Wq, const float* __restrict__ Wk,
                     const float* __restrict__ Wv,
                     unsigned short* __restrict__ Whi, unsigned short* __restrict__ Wlo) {
    int idx = blockIdx.x * 256 + threadIdx.x;
    if (idx >= 384 * 256) return;
    int row = idx >> 8, c = idx & 255;
    float f;
    if (row < 64)       f = Wq[row * 256 + c];
    else if (row < 128) f = Wk[(row - 64) * 256 + c];
    else                f = Wv[(row - 128) * 256 + c];
    unsigned short hi = f2bf(f);
    Whi[idx] = hi;
    if (row < 128) Wlo[idx] = f2bf(f - bf2f(hi));
}

// ---------------------------------------------------------------------------
// Kernel 1: projections -> fragment-blocked q(hi/lo), k(hi/lo), v.
// q scaled by log2(e) so attention softmax can use exp2.
// ---------------------------------------------------------------------------
__global__ __launch_bounds__(256, 1) void proj(
        const float* __restrict__ x, const unsigned short* __restrict__ Whi,
        const unsigned short* __restrict__ Wlo,
        const float* __restrict__ bq, const float* __restrict__ bk,
        const float* __restrict__ bv,
        unsigned short* __restrict__ qhi_ws, unsigned short* __restrict__ qlo_ws,
        unsigned short* __restrict__ khi_ws, unsigned short* __restrict__ klo_ws,
        unsigned short* __restrict__ vws) {
    __shared__ unsigned short XThi[64 * 264];
    __shared__ unsigned short XTlo[64 * 264];

    const int tid = threadIdx.x;
    const int b  = blockIdx.x >> 7;
    const int n0 = (blockIdx.x & 127) << 6;
    const float* xb = x + b * 2097152;

    for (int p = 0; p < 16; ++p) {
        int idx = p * 256 + tid;
        int c = idx >> 4, nq = idx & 15;
        float4v xv = *reinterpret_cast<const float4v*>(xb + c * 8192 + n0 + nq * 4);
#pragma unroll
        for (int q = 0; q < 4; ++q) {
            unsigned short hi = f2bf(xv[q]);
            XThi[(nq * 4 + q) * 264 + c] = hi;
            XTlo[(nq * 4 + q) * 264 + c] = f2bf(xv[q] - bf2f(hi));
        }
    }
    __syncthreads();

    const int lane = tid & 63, w = tid >> 6;
    const int quad = lane >> 4, l16 = lane & 15;

    short8 aXhi[8], aXlo[8];
#pragma unroll
    for (int ks = 0; ks < 8; ++ks) {
        aXhi[ks] = *reinterpret_cast<const short8*>(&XThi[(w * 16 + l16) * 264 + ks * 32 + quad * 8]);
        aXlo[ks] = *reinterpret_cast<const short8*>(&XTlo[(w * 16 + l16) * 264 + ks * 32 + quad * 8]);
    }

#pragma unroll
    for (int ot = 0; ot < 8; ++ot) {
        float4v acc = {0.f, 0.f, 0.f, 0.f};
#pragma unroll
        for (int ks = 0; ks < 8; ++ks) {
            short8 bwhi = *reinterpret_cast<const short8*>(&Whi[(ot * 16 + l16) * 256 + ks * 32 + quad * 8]);
            short8 bwlo = *reinterpret_cast<const short8*>(&Wlo[(ot * 16 + l16) * 256 + ks * 32 + quad * 8]);
            acc = MFMA(aXhi[ks], bwhi, acc);
            acc = MFMA(aXlo[ks], bwhi, acc);
            acc = MFMA(aXhi[ks], bwlo, acc);
        }
        int o = ot * 16 + l16;
        float bias = (ot < 4) ? bq[o] : bk[o - 64];
#pragma unroll
        for (int r = 0; r < 4; ++r) {
            int n = n0 + w * 16 + quad * 4 + r;
            float y = acc[r] + bias;
            if (ot < 4) y *= LOG2E;
            unsigned short hi = f2bf(y);
            unsigned short lo = f2bf(y - bf2f(hi));
            if (ot < 4) {
                int id = qk_idx(b, n, o);
                qhi_ws[id] = hi; qlo_ws[id] = lo;
            } else {
                int id = qk_idx(b, n, o - 64);
                khi_ws[id] = hi; klo_ws[id] = lo;
            }
        }
    }

    float4v acc2[4][4];
#pragma unroll
    for (int mt = 0; mt < 4; ++mt)
#pragma unroll
        for (int nt = 0; nt < 4; ++nt) acc2[mt][nt] = (float4v){0.f, 0.f, 0.f, 0.f};

#pragma unroll
    for (int ks = 0; ks < 8; ++ks) {
        short8 aW[4], bX[4];
#pragma unroll
        for (int mt = 0; mt < 4; ++mt)
            aW[mt] = *reinterpret_cast<const short8*>(&Whi[(128 + w * 64 + mt * 16 + l16) * 256 + ks * 32 + quad * 8]);
#pragma unroll
        for (int nt = 0; nt < 4; ++nt)
            bX[nt] = *reinterpret_cast<const short8*>(&XThi[(nt * 16 + l16) * 264 + ks * 32 + quad * 8]);
#pragma unroll
        for (int mt = 0; mt < 4; ++mt)
#pragma unroll
            for (int nt = 0; nt < 4; ++nt)
                acc2[mt][nt] = MFMA(aW[mt], bX[nt], acc2[mt][nt]);
    }
#pragma unroll
    for (int mt = 0; mt < 4; ++mt) {
#pragma unroll
        for (int r = 0; r < 4; ++r) {
            int c = w * 64 + mt * 16 + quad * 4 + r;
            float bias = bv[c];
#pragma unroll
            for (int nt = 0; nt < 4; ++nt) {
                int n = n0 + nt * 16 + l16;
                vws[v_idx(b, c, n)] = f2bf(acc2[mt][nt][r] + bias);
            }
        }
    }
}

// ---------------------------------------------------------------------------
// Kernel 2: flash attention. BJ=32, 256-thread / 4-wave blocks, grid 512,
// 2 blocks/CU. Counted-vmcnt pipeline (T3/T4), conflict-free P (pitch 36).
//   body t: VMWAIT(4) -> s_barrier -> issue K(t+1) [2-buf] THEN V(t+1)
//   [3-buf] -> QK(t) -> deferred PV(t-1) -> softmax(t) -> P stash.
// vmcnt ledger (FIFO, K-first issue order is load-bearing): top of body t
// outstanding = [V(t-1)x4, K(t)x2, V(t)x4]; vmcnt(4) retires exactly
// V(t-1)+K(t) = this body's needs, V(t) stays in flight across the barrier.
// K 1-body slack (~2200cy) >> HBM-miss latency (~900cy) -> sufficient.
// WAW: K(t+1) overwrites K(t-1) (read body t-1, barrier passed); V(t+1)
// overwrites V(t-2) (read body t-1, barrier passed).
// P pitch 36: quad stride 288B -> banks 8*quad + (l16>>1), 2 lanes/bank
// (free); pitch 32 was 8-way on writes / 4-way on aP reads (r4's 5.24M
// conflicts). LDS = 48K V + 16K K + 9K P = 73KB -> 2 blocks/CU.
// Deferred-PV, no-max softmax, setprio around MFMA clusters (T5).
// ---------------------------------------------------------------------------
__global__ __launch_bounds__(256, 2) void attn(
        const unsigned short* __restrict__ qhi_ws, const unsigned short* __restrict__ qlo_ws,
        const unsigned short* __restrict__ khi_ws, const unsigned short* __restrict__ klo_ws,
        const unsigned short* __restrict__ vws,
        unsigned short* __restrict__ Opart, float* __restrict__ ml) {
    __shared__ unsigned short Vlds[3][8192];    // 3 x 16KB V tiles (32 j x 256 c)
    __shared__ unsigned short Klds[2][4096];    // 2 x 8KB K tiles (hi 4 frags | lo 4 frags)
    __shared__ unsigned short Pl[4 * 32 * 36];  // per-wave P regions, pitch 36

    const int tid = threadIdx.x, lane = tid & 63, w = tid >> 6;  // w: 0..3
    const int quad = lane >> 4, l16 = lane & 15;
    const int xcd = blockIdx.x & 7, b = xcd & 1, jr = xcd >> 1;
    const int it = blockIdx.x >> 3;             // 0..63, 128 rows each
    const int iw16 = it * 8 + w * 2;            // wave's i-frag base
    unsigned short* Pw = Pl + w * (32 * 36);

    // Q fragments resident (8 b128 total)
    const unsigned short* qhb = qhi_ws + (size_t)((b * 512 + iw16) * 2) * 512 + lane * 8;
    const unsigned short* qlb = qlo_ws + (size_t)((b * 512 + iw16) * 2) * 512 + lane * 8;
    short8 qh[2][2], ql[2][2];
#pragma unroll
    for (int mt = 0; mt < 2; ++mt)
#pragma unroll
        for (int kf = 0; kf < 2; ++kf) {
            qh[mt][kf] = *reinterpret_cast<const short8*>(qhb + (mt * 2 + kf) * 512);
            ql[mt][kf] = *reinterpret_cast<const short8*>(qlb + (mt * 2 + kf) * 512);
        }

    // staging: wave w stages K hi-frag w + K lo-frag w (1KB each) and
    // 4 x 1KB V chunks per tile.
    const unsigned short* khs = khi_ws + (size_t)((b * 512 + jr * 128) * 2) * 512 + w * 512 + lane * 8;
    const unsigned short* kls = klo_ws + (size_t)((b * 512 + jr * 128) * 2) * 512 + w * 512 + lane * 8;
    const unsigned short* vstage = vws + ((size_t)(b * 256 + jr * 64) * 16 + w * 4) * 512 + lane * 8;

    float4v acc[2][16];
#pragma unroll
    for (int mt = 0; mt < 2; ++mt)
#pragma unroll
        for (int cf = 0; cf < 16; ++cf) acc[mt][cf] = (float4v){0.f, 0.f, 0.f, 0.f};
    float lrow[2][4];
    short8 aP[2];
#pragma unroll
    for (int mt = 0; mt < 2; ++mt)
#pragma unroll
        for (int r = 0; r < 4; ++r) lrow[mt][r] = 0.f;

    // prologue (FIFO): [K(0) x2][V(0) x4] -> at iter0's vmcnt(4): K(0) done,
    // V(0) may still be in flight (first needed by PV in body 1).
    GLOAD_LDS16(khs, &Klds[0][w * 512]);
    GLOAD_LDS16(kls, &Klds[0][2048 + w * 512]);
#pragma unroll
    for (int q = 0; q < 4; ++q)
        GLOAD_LDS16(vstage + q * 512, &Vlds[0][(w * 4 + q) * 512]);
    khs += 2048; kls += 2048; vstage += 8192;

    int bprev = 2, bcur = 0, bnext = 1;   // V buffer rotation
#pragma unroll 1
    for (int itn = 0; itn < 64; ++itn) {
        // ---- counted wait + barrier: retires V(itn-1)+K(itn) exactly;
        //      V(itn) (newest 4) stays in flight across the barrier.
        VMWAIT("4");
        __builtin_amdgcn_s_barrier();
        __builtin_amdgcn_sched_barrier(0);

        // ---- issue K(itn+1) FIRST, then V(itn+1) (order = vmcnt ledger) ----
        if (itn < 63) {
            GLOAD_LDS16(khs, &Klds[(itn + 1) & 1][w * 512]);
            GLOAD_LDS16(kls, &Klds[(itn + 1) & 1][2048 + w * 512]);
            khs += 2048; kls += 2048;
#pragma unroll
            for (int q = 0; q < 4; ++q)
                GLOAD_LDS16(vstage + q * 512, &Vlds[bnext][(w * 4 + q) * 512]);
            vstage += 8192;
        }

        // ---- QK^T (split-bf16) from LDS K, 24 MFMA ----
        const unsigned short* Kc = &Klds[itn & 1][0];
        float4v s[2][2];
#pragma unroll
        for (int mt = 0; mt < 2; ++mt)
#pragma unroll
            for (int jt = 0; jt < 2; ++jt) s[mt][jt] = (float4v){0.f, 0.f, 0.f, 0.f};
        __builtin_amdgcn_s_setprio(1);
#pragma unroll
        for (int jt = 0; jt < 2; ++jt) {
            short8 kh0 = *reinterpret_cast<const short8*>(Kc + (jt * 2 + 0) * 512 + lane * 8);
            short8 kh1 = *reinterpret_cast<const short8*>(Kc + (jt * 2 + 1) * 512 + lane * 8);
            short8 kl0 = *reinterpret_cast<const short8*>(Kc + 2048 + (jt * 2 + 0) * 512 + lane * 8);
            short8 kl1 = *reinterpret_cast<const short8*>(Kc + 2048 + (jt * 2 + 1) * 512 + lane * 8);
#pragma unroll
            for (int mt = 0; mt < 2; ++mt) {
                s[mt][jt] = MFMA(qh[mt][0], kh0, s[mt][jt]);
                s[mt][jt] = MFMA(ql[mt][0], kh0, s[mt][jt]);
                s[mt][jt] = MFMA(qh[mt][0], kl0, s[mt][jt]);
                s[mt][jt] = MFMA(qh[mt][1], kh1, s[mt][jt]);
                s[mt][jt] = MFMA(ql[mt][1], kh1, s[mt][jt]);
                s[mt][jt] = MFMA(qh[mt][1], kl1, s[mt][jt]);
            }
        }
        __builtin_amdgcn_s_setprio(0);

        // ---- deferred PV(itn-1): 32 MFMA, independent of softmax below ----
        if (itn) {
            const unsigned short* vl = &Vlds[bprev][0];
            __builtin_amdgcn_s_setprio(1);
#pragma unroll
            for (int cf = 0; cf < 16; ++cf) {
                short8 v0 = *reinterpret_cast<const short8*>(vl + cf * 512 + lane * 8);
                acc[0][cf] = MFMA(aP[0], v0, acc[0][cf]);
                acc[1][cf] = MFMA(aP[1], v0, acc[1][cf]);
            }
            __builtin_amdgcn_s_setprio(0);
        }

        // ---- no-max softmax(itn): p = exp2(s), lane-local l, packed cvt ----
#pragma unroll
        for (int mt = 0; mt < 2; ++mt)
#pragma unroll
            for (int jt = 0; jt < 2; ++jt) {
                float p0 = exp2f(s[mt][jt][0]);
                float p1 = exp2f(s[mt][jt][1]);
                float p2 = exp2f(s[mt][jt][2]);
                float p3 = exp2f(s[mt][jt][3]);
                lrow[mt][0] += p0; lrow[mt][1] += p1;
                lrow[mt][2] += p2; lrow[mt][3] += p3;
                unsigned u01 = pk2bf(p0, p1);
                unsigned u23 = pk2bf(p2, p3);
                int base = (mt * 16 + quad * 4) * 36 + jt * 16 + l16;
                Pw[base]       = (unsigned short)u01;
                Pw[base + 36]  = (unsigned short)(u01 >> 16);
                Pw[base + 72]  = (unsigned short)u23;
                Pw[base + 108] = (unsigned short)(u23 >> 16);
            }

        // ---- stash P(itn) as A-frags for next iteration's PV ----
#pragma unroll
        for (int mt = 0; mt < 2; ++mt)
            aP[mt] = *reinterpret_cast<const short8*>(&Pw[(mt * 16 + l16) * 36 + quad * 8]);

        int t = bprev; bprev = bcur; bcur = bnext; bnext = t;
    }

    // ---- final PV(63): V(63) still in flight -> full drain ----
    VMWAIT("0");
    __builtin_amdgcn_s_barrier();
    __builtin_amdgcn_sched_barrier(0);
    {
        const unsigned short* vl = &Vlds[bprev][0];
#pragma unroll
        for (int cf = 0; cf < 16; ++cf) {
            short8 v0 = *reinterpret_cast<const short8*>(vl + cf * 512 + lane * 8);
            acc[0][cf] = MFMA(aP[0], v0, acc[0][cf]);
            acc[1][cf] = MFMA(aP[1], v0, acc[1][cf]);
        }
    }

    // ---- final l reduction over the 16-lane j-groups; store l ----
#pragma unroll
    for (int mt = 0; mt < 2; ++mt)
#pragma unroll
        for (int r = 0; r < 4; ++r) {
            float lv = lrow[mt][r];
            lv += __shfl_xor(lv, 1);
            lv += __shfl_xor(lv, 2);
            lv += __shfl_xor(lv, 4);
            lv += __shfl_xor(lv, 8);
            if (l16 == 0) {
                int iloc = w * 32 + mt * 16 + quad * 4 + r;
                ml[blockIdx.x * 128 + iloc] = lv;
            }
        }

    // ---- store unnormalized partial O (bf16, packed cvt) ----
    unsigned short* ob = Opart + (size_t)blockIdx.x * 32768;
#pragma unroll
    for (int mt = 0; mt < 2; ++mt)
#pragma unroll
        for (int cf = 0; cf < 16; ++cf) {
            unsigned u01 = pk2bf(acc[mt][cf][0], acc[mt][cf][1]);
            unsigned u23 = pk2bf(acc[mt][cf][2], acc[mt][cf][3]);
            int iloc = w * 32 + mt * 16 + quad * 4;
            ob[(iloc + 0) * 256 + cf * 16 + l16] = (unsigned short)u01;
            ob[(iloc + 1) * 256 + cf * 16 + l16] = (unsigned short)(u01 >> 16);
            ob[(iloc + 2) * 256 + cf * 16 + l16] = (unsigned short)u23;
            ob[(iloc + 3) * 256 + cf * 16 + l16] = (unsigned short)(u23 >> 16);
        }
}

// ---------------------------------------------------------------------------
// Kernel 3: combine 4 j-split partials + residual. m==0 path: single factor
// 1/sum(l). Grid 512 = (b, cc 0..3, it 0..63); block covers 64 c x 128 i.
// ---------------------------------------------------------------------------
__global__ __launch_bounds__(256) void combine(
        const unsigned short* __restrict__ Opart, const float* __restrict__ ml,
        const float* __restrict__ x, float* __restrict__ out) {
    __shared__ float fac[128];
    __shared__ float trans[64 * 130];  // [c][i], pitch 130

    const int t = threadIdx.x;
    const int blk = blockIdx.x;
    const int b = blk & 1, cc = (blk >> 1) & 3, it = blk >> 3;

    if (t < 128) {
        float sum = 0.f;
#pragma unroll
        for (int s = 0; s < 4; ++s)
            sum += ml[(size_t)((it << 3) | (s << 1) | b) * 128 + t];
        fac[t] = 1.0f / sum;
    }
    __syncthreads();

    // accumulate 4 partials (vectorized short8 loads), scale, LDS transpose
    {
        const int cgrp = t & 7, irow = t >> 3;  // 8 c-groups x 32 i-slots
#pragma unroll
        for (int ip = 0; ip < 4; ++ip) {
            int i = ip * 32 + irow;
            float a[8];
#pragma unroll
            for (int e = 0; e < 8; ++e) a[e] = 0.f;
#pragma unroll
            for (int s = 0; s < 4; ++s) {
                const unsigned short* op = Opart +
                    (size_t)((it << 3) | (s << 1) | b) * 32768 + i * 256 + cc * 64 + cgrp * 8;
                short8 o = *reinterpret_cast<const short8*>(op);
#pragma unroll
                for (int e = 0; e < 8; ++e) a[e] += bf2f((unsigned short)o[e]);
            }
            float f = fac[i];
#pragma unroll
            for (int e = 0; e < 8; ++e) trans[(cgrp * 8 + e) * 130 + i] = a[e] * f;
        }
    }
    __syncthreads();

    // coalesced residual + store
    {
        const int c2 = t >> 2, iq = t & 3;
        const int cg = cc * 64 + c2;
        const float* xr = x + (size_t)b * 2097152 + (size_t)cg * 8192 + it * 128;
        float* orow = out + (size_t)b * 2097152 + (size_t)cg * 8192 + it * 128;
#pragma unroll 2
        for (int k = 0; k < 8; ++k) {
            int i = iq * 4 + k * 16;
            float4v o;
#pragma unroll
            for (int r = 0; r < 4; ++r) o[r] = trans[c2 * 130 + i + r];
            float4v xv = *reinterpret_cast<const float4v*>(xr + i);
#pragma unroll
            for (int r = 0; r < 4; ++r) o[r] += xv[r];
            *reinterpret_cast<float4v*>(orow + i) = o;
        }
    }
}

// ---------------------------------------------------------------------------
extern "C" void kernel_launch(void* const* d_in, const int* in_sizes, int n_in,
                              void* d_out, int out_size, void* d_ws, size_t ws_size,
                              hipStream_t stream) {
    const float* x  = (const float*)d_in[0];
    const float* Wq = (const float*)d_in[1];
    const float* bq = (const float*)d_in[2];
    const float* Wk = (const float*)d_in[3];
    const float* bk = (const float*)d_in[4];
    const float* Wv = (const float*)d_in[5];
    const float* bv = (const float*)d_in[6];

    unsigned short* Whi = (unsigned short*)d_ws;           // 384*256
    unsigned short* Wlo = Whi + 384 * 256;                 // 128*256
    unsigned short* qhi = Wlo + 128 * 256;                 // [2][8192][64] blocked
    unsigned short* qlo = qhi + 2 * 8192 * 64;
    unsigned short* khi = qlo + 2 * 8192 * 64;
    unsigned short* klo = khi + 2 * 8192 * 64;
    unsigned short* vws = klo + 2 * 8192 * 64;             // [2][256][8192] blocked
    unsigned short* Opart = vws + 2 * 256 * 8192;          // 512 blk * 128 i * 256 c bf16
    float* ml = (float*)(Opart + (size_t)512 * 32768);     // 512 blk * 128

    wcvt<<<384, 256, 0, stream>>>(Wq, Wk, Wv, Whi, Wlo);
    proj<<<256, 256, 0, stream>>>(x, Whi, Wlo, bq, bk, bv, qhi, qlo, khi, klo, vws);
    attn<<<512, 256, 0, stream>>>(qhi, qlo, khi, klo, vws, Opart, ml);
    combine<<<512, 256, 0, stream>>>(Opart, ml, x, (float*)d_out);
}

// Round 6
// 226.403 us; speedup vs baseline: 1.0554x; 1.0554x over previous
//
#include <hip/hip_runtime.h>
#include <hip/hip_bf16.h>

typedef short short8 __attribute__((ext_vector_type(8)));
typedef float float4v __attribute__((ext_vector_type(4)));

#define MFMA(a, b, c) __builtin_amdgcn_mfma_f32_16x16x32_bf16((a), (b), (c), 0, 0, 0)

typedef const __attribute__((address_space(1))) unsigned int gu32;
typedef __attribute__((address_space(3))) unsigned int lu32;
#define GLOAD_LDS16(g, l) __builtin_amdgcn_global_load_lds((gu32*)(g), (lu32*)(l), 16, 0, 0)

// counted vmem wait: keeps newest N loads in flight across the barrier
#define VMWAIT(n) asm volatile("s_waitcnt vmcnt(" n ")" ::: "memory")

#define LOG2E 1.4426950408889634f

static __device__ __forceinline__ unsigned short f2bf(float f) {
    union { float f; unsigned u; } v; v.f = f;
    unsigned r = (v.u + 0x7fffu + ((v.u >> 16) & 1u)) >> 16;
    return (unsigned short)r;
}
static __device__ __forceinline__ float bf2f(unsigned short h) {
    union { unsigned u; float f; } v; v.u = ((unsigned)h) << 16;
    return v.f;
}
// packed RNE fp32x2 -> bf16x2 (single v_cvt_pk on gfx950)
static __device__ __forceinline__ unsigned pk2bf(float a, float b) {
    union { __hip_bfloat162 h; unsigned u; } cv;
    cv.h = __float22bfloat162_rn(make_float2(a, b));
    return cv.u;
}

// Fragment-blocked layouts: each MFMA fragment (16 rows x 32 k) = 1024
// contiguous bytes; lane i's 16B piece at offset i*16.
static __device__ __forceinline__ int qk_idx(int b, int n, int o) {
    int frag = (b * 512 + (n >> 4)) * 2 + (o >> 5);
    return frag * 512 + ((o >> 3) & 3) * 128 + (n & 15) * 8 + (o & 7);
}
static __device__ __forceinline__ int v_idx(int b, int c, int n) {
    int frag = (b * 256 + (n >> 5)) * 16 + (c >> 4);
    return frag * 512 + ((n >> 3) & 3) * 128 + (c & 15) * 8 + (n & 7);
}

// ---------------------------------------------------------------------------
// Kernel 0: weights fp32 -> bf16 (hi for all; lo for Wq/Wk split path)
// ---------------------------------------------------------------------------
__global__ void wcvt(const float* __restrict__ Wq, const float* __restrict__ Wk,
                     const float* __restrict__ Wv,
                     unsigned short* __restrict__ Whi, unsigned short* __restrict__ Wlo) {
    int idx = blockIdx.x * 256 + threadIdx.x;
    if (idx >= 384 * 256) return;
    int row = idx >> 8, c = idx & 255;
    float f;
    if (row < 64)       f = Wq[row * 256 + c];
    else if (row < 128) f = Wk[(row - 64) * 256 + c];
    else                f = Wv[(row - 128) * 256 + c];
    unsigned short hi = f2bf(f);
    Whi[idx] = hi;
    if (row < 128) Wlo[idx] = f2bf(f - bf2f(hi));
}

// ---------------------------------------------------------------------------
// Kernel 1: projections -> fragment-blocked q(hi/lo), k(hi/lo), v.
// q scaled by log2(e) so attention softmax can use exp2.
// K rows are sigma-PERMUTED within each 32-row tile:
//   sigma(j) = ((j&4)<<2) | ((j>>3)<<2) | (j&3)
// so that the attention kernel's SWAPPED QK^T (mfma(K,Q)) emits P with
// j = quad*8 + (jt*4+r) per lane == exactly the PV A-fragment layout.
// (softmax sums over j are permutation-invariant; V is NOT permuted and
// matches because the A-frag k-position equals the actual j.)
// ---------------------------------------------------------------------------
__global__ __launch_bounds__(256, 1) void proj(
        const float* __restrict__ x, const unsigned short* __restrict__ Whi,
        const unsigned short* __restrict__ Wlo,
        const float* __restrict__ bq, const float* __restrict__ bk,
        const float* __restrict__ bv,
        unsigned short* __restrict__ qhi_ws, unsigned short* __restrict__ qlo_ws,
        unsigned short* __restrict__ khi_ws, unsigned short* __restrict__ klo_ws,
        unsigned short* __restrict__ vws) {
    __shared__ unsigned short XThi[64 * 264];
    __shared__ unsigned short XTlo[64 * 264];

    const int tid = threadIdx.x;
    const int b  = blockIdx.x >> 7;
    const int n0 = (blockIdx.x & 127) << 6;
    const float* xb = x + b * 2097152;

    for (int p = 0; p < 16; ++p) {
        int idx = p * 256 + tid;
        int c = idx >> 4, nq = idx & 15;
        float4v xv = *reinterpret_cast<const float4v*>(xb + c * 8192 + n0 + nq * 4);
#pragma unroll
        for (int q = 0; q < 4; ++q) {
            unsigned short hi = f2bf(xv[q]);
            XThi[(nq * 4 + q) * 264 + c] = hi;
            XTlo[(nq * 4 + q) * 264 + c] = f2bf(xv[q] - bf2f(hi));
        }
    }
    __syncthreads();

    const int lane = tid & 63, w = tid >> 6;
    const int quad = lane >> 4, l16 = lane & 15;

    short8 aXhi[8], aXlo[8];
#pragma unroll
    for (int ks = 0; ks < 8; ++ks) {
        aXhi[ks] = *reinterpret_cast<const short8*>(&XThi[(w * 16 + l16) * 264 + ks * 32 + quad * 8]);
        aXlo[ks] = *reinterpret_cast<const short8*>(&XTlo[(w * 16 + l16) * 264 + ks * 32 + quad * 8]);
    }

#pragma unroll
    for (int ot = 0; ot < 8; ++ot) {
        float4v acc = {0.f, 0.f, 0.f, 0.f};
#pragma unroll
        for (int ks = 0; ks < 8; ++ks) {
            short8 bwhi = *reinterpret_cast<const short8*>(&Whi[(ot * 16 + l16) * 256 + ks * 32 + quad * 8]);
            short8 bwlo = *reinterpret_cast<const short8*>(&Wlo[(ot * 16 + l16) * 256 + ks * 32 + quad * 8]);
            acc = MFMA(aXhi[ks], bwhi, acc);
            acc = MFMA(aXlo[ks], bwhi, acc);
            acc = MFMA(aXhi[ks], bwlo, acc);
        }
        int o = ot * 16 + l16;
        float bias = (ot < 4) ? bq[o] : bk[o - 64];
#pragma unroll
        for (int r = 0; r < 4; ++r) {
            int n = n0 + w * 16 + quad * 4 + r;
            float y = acc[r] + bias;
            if (ot < 4) y *= LOG2E;
            unsigned short hi = f2bf(y);
            unsigned short lo = f2bf(y - bf2f(hi));
            if (ot < 4) {
                int id = qk_idx(b, n, o);
                qhi_ws[id] = hi; qlo_ws[id] = lo;
            } else {
                int j = n & 31;
                int nper = (n & ~31) | ((j & 4) << 2) | ((j >> 3) << 2) | (j & 3);
                int id = qk_idx(b, nper, o - 64);
                khi_ws[id] = hi; klo_ws[id] = lo;
            }
        }
    }

    float4v acc2[4][4];
#pragma unroll
    for (int mt = 0; mt < 4; ++mt)
#pragma unroll
        for (int nt = 0; nt < 4; ++nt) acc2[mt][nt] = (float4v){0.f, 0.f, 0.f, 0.f};

#pragma unroll
    for (int ks = 0; ks < 8; ++ks) {
        short8 aW[4], bX[4];
#pragma unroll
        for (int mt = 0; mt < 4; ++mt)
            aW[mt] = *reinterpret_cast<const short8*>(&Whi[(128 + w * 64 + mt * 16 + l16) * 256 + ks * 32 + quad * 8]);
#pragma unroll
        for (int nt = 0; nt < 4; ++nt)
            bX[nt] = *reinterpret_cast<const short8*>(&XThi[(nt * 16 + l16) * 264 + ks * 32 + quad * 8]);
#pragma unroll
        for (int mt = 0; mt < 4; ++mt)
#pragma unroll
            for (int nt = 0; nt < 4; ++nt)
                acc2[mt][nt] = MFMA(aW[mt], bX[nt], acc2[mt][nt]);
    }
#pragma unroll
    for (int mt = 0; mt < 4; ++mt) {
#pragma unroll
        for (int r = 0; r < 4; ++r) {
            int c = w * 64 + mt * 16 + quad * 4 + r;
            float bias = bv[c];
#pragma unroll
            for (int nt = 0; nt < 4; ++nt) {
                int n = n0 + nt * 16 + l16;
                vws[v_idx(b, c, n)] = f2bf(acc2[mt][nt][r] + bias);
            }
        }
    }
}

// ---------------------------------------------------------------------------
// Kernel 2: flash attention. BJ=32, 256-thread / 4-wave blocks, grid 512,
// 2 blocks/CU. SWAPPED QK^T (mfma(K,Q)) + sigma-permuted K storage puts P
// directly in the PV A-fragment layout: per lane, p[jt*4+r] = P[j=quad*8+
// jt*4+r][i=l16]. aP is built with 4 pk2bf per mt -- NO P LDS round-trip
// (the 16 ds_write + lgkm + 2 ds_read chain is gone), softmax l is a single
// per-lane scalar per mt (i=l16 fixed), reduced with 2 shuffles.
// Freed 9KB LDS funds K 3-buffer DEPTH-2 prefetch (r4's proven ledger):
//   body t: VMWAIT(6) -> s_barrier -> issue V(t+1)[3-buf] + K(t+2)[3-buf].
// vmcnt ledger (FIFO): top of body t outstanding = [V(t-1)x4, K(t)x2,
// V(t)x4, K(t+1)x2]; vmcnt(6) retires exactly V(t-1)+K(t) = body t's needs.
// LDS = 48K V + 24K K = 72KB -> 2 blocks/CU.
// Deferred-PV, no-max softmax, setprio around MFMA clusters (T5).
// ---------------------------------------------------------------------------
__global__ __launch_bounds__(256, 2) void attn(
        const unsigned short* __restrict__ qhi_ws, const unsigned short* __restrict__ qlo_ws,
        const unsigned short* __restrict__ khi_ws, const unsigned short* __restrict__ klo_ws,
        const unsigned short* __restrict__ vws,
        unsigned short* __restrict__ Opart, float* __restrict__ ml) {
    __shared__ unsigned short Vlds[3][8192];    // 3 x 16KB V tiles (32 j x 256 c)
    __shared__ unsigned short Klds[3][4096];    // 3 x 8KB K tiles (hi 4 frags | lo 4 frags)

    const int tid = threadIdx.x, lane = tid & 63, w = tid >> 6;  // w: 0..3
    const int quad = lane >> 4, l16 = lane & 15;
    const int xcd = blockIdx.x & 7, b = xcd & 1, jr = xcd >> 1;
    const int it = blockIdx.x >> 3;             // 0..63, 128 rows each
    const int iw16 = it * 8 + w * 2;            // wave's i-frag base

    // Q fragments resident (8 b128 total)
    const unsigned short* qhb = qhi_ws + (size_t)((b * 512 + iw16) * 2) * 512 + lane * 8;
    const unsigned short* qlb = qlo_ws + (size_t)((b * 512 + iw16) * 2) * 512 + lane * 8;
    short8 qh[2][2], ql[2][2];
#pragma unroll
    for (int mt = 0; mt < 2; ++mt)
#pragma unroll
        for (int kf = 0; kf < 2; ++kf) {
            qh[mt][kf] = *reinterpret_cast<const short8*>(qhb + (mt * 2 + kf) * 512);
            ql[mt][kf] = *reinterpret_cast<const short8*>(qlb + (mt * 2 + kf) * 512);
        }

    // staging: wave w stages K hi-frag w + K lo-frag w (1KB each) and
    // 4 x 1KB V chunks per tile.
    const unsigned short* khs = khi_ws + (size_t)((b * 512 + jr * 128) * 2) * 512 + w * 512 + lane * 8;
    const unsigned short* kls = klo_ws + (size_t)((b * 512 + jr * 128) * 2) * 512 + w * 512 + lane * 8;
    const unsigned short* vstage = vws + ((size_t)(b * 256 + jr * 64) * 16 + w * 4) * 512 + lane * 8;

    float4v acc[2][16];
#pragma unroll
    for (int mt = 0; mt < 2; ++mt)
#pragma unroll
        for (int cf = 0; cf < 16; ++cf) acc[mt][cf] = (float4v){0.f, 0.f, 0.f, 0.f};
    float lrow[2] = {0.f, 0.f};
    short8 aP[2];

    // prologue issue order (FIFO matters for vmcnt counting):
    //   [K(0) x2][V(0) x4][K(1) x2]
    GLOAD_LDS16(khs, &Klds[0][w * 512]);
    GLOAD_LDS16(kls, &Klds[0][2048 + w * 512]);
#pragma unroll
    for (int q = 0; q < 4; ++q)
        GLOAD_LDS16(vstage + q * 512, &Vlds[0][(w * 4 + q) * 512]);
    GLOAD_LDS16(khs + 2048, &Klds[1][w * 512]);
    GLOAD_LDS16(kls + 2048, &Klds[1][2048 + w * 512]);
    khs += 4096; kls += 4096; vstage += 8192;

    int bprev = 2, bcur = 0, bnext = 1;   // V buffer rotation
    int kc = 0, kst = 2;                  // K current / K stage-target buffers
#pragma unroll 1
    for (int itn = 0; itn < 64; ++itn) {
        // ---- counted wait + barrier: retires V(itn-1)+K(itn) exactly;
        //      newest batches (V(itn), K(itn+1)) stay in flight.
        if (itn < 63) VMWAIT("6");
        else          VMWAIT("4");   // tail: only V(63) may remain in flight
        __builtin_amdgcn_s_barrier();
        __builtin_amdgcn_sched_barrier(0);

        // ---- issue V(itn+1) then K(itn+2) (2-body slack each) ----
        if (itn < 63) {
#pragma unroll
            for (int q = 0; q < 4; ++q)
                GLOAD_LDS16(vstage + q * 512, &Vlds[bnext][(w * 4 + q) * 512]);
            vstage += 8192;
        }
        if (itn < 62) {
            GLOAD_LDS16(khs, &Klds[kst][w * 512]);
            GLOAD_LDS16(kls, &Klds[kst][2048 + w * 512]);
            khs += 2048; kls += 2048;
        }

        // ---- QK^T SWAPPED (A=K, B=Q), 24 MFMA ----
        // s[mt][jt][r] = P[j = quad*8 + jt*4 + r][i = mt block, col l16]
        const unsigned short* Kc = &Klds[kc][0];
        float4v s[2][2];
#pragma unroll
        for (int mt = 0; mt < 2; ++mt)
#pragma unroll
            for (int jt = 0; jt < 2; ++jt) s[mt][jt] = (float4v){0.f, 0.f, 0.f, 0.f};
        __builtin_amdgcn_s_setprio(1);
#pragma unroll
        for (int jt = 0; jt < 2; ++jt) {
            short8 kh0 = *reinterpret_cast<const short8*>(Kc + (jt * 2 + 0) * 512 + lane * 8);
            short8 kh1 = *reinterpret_cast<const short8*>(Kc + (jt * 2 + 1) * 512 + lane * 8);
            short8 kl0 = *reinterpret_cast<const short8*>(Kc + 2048 + (jt * 2 + 0) * 512 + lane * 8);
            short8 kl1 = *reinterpret_cast<const short8*>(Kc + 2048 + (jt * 2 + 1) * 512 + lane * 8);
#pragma unroll
            for (int mt = 0; mt < 2; ++mt) {
                s[mt][jt] = MFMA(kh0, qh[mt][0], s[mt][jt]);
                s[mt][jt] = MFMA(kh0, ql[mt][0], s[mt][jt]);
                s[mt][jt] = MFMA(kl0, qh[mt][0], s[mt][jt]);
                s[mt][jt] = MFMA(kh1, qh[mt][1], s[mt][jt]);
                s[mt][jt] = MFMA(kh1, ql[mt][1], s[mt][jt]);
                s[mt][jt] = MFMA(kl1, qh[mt][1], s[mt][jt]);
            }
        }
        __builtin_amdgcn_s_setprio(0);

        // ---- deferred PV(itn-1): 32 MFMA, independent of softmax below ----
        if (itn) {
            const unsigned short* vl = &Vlds[bprev][0];
            __builtin_amdgcn_s_setprio(1);
#pragma unroll
            for (int cf = 0; cf < 16; ++cf) {
                short8 v0 = *reinterpret_cast<const short8*>(vl + cf * 512 + lane * 8);
                acc[0][cf] = MFMA(aP[0], v0, acc[0][cf]);
                acc[1][cf] = MFMA(aP[1], v0, acc[1][cf]);
            }
            __builtin_amdgcn_s_setprio(0);
        }

        // ---- no-max softmax(itn): p = exp2(s); aP built IN-REGISTER ----
#pragma unroll
        for (int mt = 0; mt < 2; ++mt) {
            float p0 = exp2f(s[mt][0][0]);
            float p1 = exp2f(s[mt][0][1]);
            float p2 = exp2f(s[mt][0][2]);
            float p3 = exp2f(s[mt][0][3]);
            float p4 = exp2f(s[mt][1][0]);
            float p5 = exp2f(s[mt][1][1]);
            float p6 = exp2f(s[mt][1][2]);
            float p7 = exp2f(s[mt][1][3]);
            lrow[mt] += (p0 + p1) + (p2 + p3) + (p4 + p5) + (p6 + p7);
            union { short8 s8; unsigned u[4]; } ap;
            ap.u[0] = pk2bf(p0, p1);
            ap.u[1] = pk2bf(p2, p3);
            ap.u[2] = pk2bf(p4, p5);
            ap.u[3] = pk2bf(p6, p7);
            aP[mt] = ap.s8;
        }

        int t = bprev; bprev = bcur; bcur = bnext; bnext = t;
        kc  = (kc  == 2) ? 0 : kc + 1;
        kst = (kst == 2) ? 0 : kst + 1;
    }

    // ---- final PV(63): V(63) may still be in flight -> full drain ----
    VMWAIT("0");
    __builtin_amdgcn_s_barrier();
    __builtin_amdgcn_sched_barrier(0);
    {
        const unsigned short* vl = &Vlds[bprev][0];
#pragma unroll
        for (int cf = 0; cf < 16; ++cf) {
            short8 v0 = *reinterpret_cast<const short8*>(vl + cf * 512 + lane * 8);
            acc[0][cf] = MFMA(aP[0], v0, acc[0][cf]);
            acc[1][cf] = MFMA(aP[1], v0, acc[1][cf]);
        }
    }

    // ---- final l reduction across quads (j-partials); store l ----
#pragma unroll
    for (int mt = 0; mt < 2; ++mt) {
        float lv = lrow[mt];
        lv += __shfl_xor(lv, 16);
        lv += __shfl_xor(lv, 32);
        if (quad == 0)
            ml[blockIdx.x * 128 + w * 32 + mt * 16 + l16] = lv;
    }

    // ---- store unnormalized partial O (bf16, packed cvt) ----
    unsigned short* ob = Opart + (size_t)blockIdx.x * 32768;
#pragma unroll
    for (int mt = 0; mt < 2; ++mt)
#pragma unroll
        for (int cf = 0; cf < 16; ++cf) {
            unsigned u01 = pk2bf(acc[mt][cf][0], acc[mt][cf][1]);
            unsigned u23 = pk2bf(acc[mt][cf][2], acc[mt][cf][3]);
            int iloc = w * 32 + mt * 16 + quad * 4;
            ob[(iloc + 0) * 256 + cf * 16 + l16] = (unsigned short)u01;
            ob[(iloc + 1) * 256 + cf * 16 + l16] = (unsigned short)(u01 >> 16);
            ob[(iloc + 2) * 256 + cf * 16 + l16] = (unsigned short)u23;
            ob[(iloc + 3) * 256 + cf * 16 + l16] = (unsigned short)(u23 >> 16);
        }
}

// ---------------------------------------------------------------------------
// Kernel 3: combine 4 j-split partials + residual. m==0 path: single factor
// 1/sum(l). Grid 512 = (b, cc 0..3, it 0..63); block covers 64 c x 128 i.
// ---------------------------------------------------------------------------
__global__ __launch_bounds__(256) void combine(
        const unsigned short* __restrict__ Opart, const float* __restrict__ ml,
        const float* __restrict__ x, float* __restrict__ out) {
    __shared__ float fac[128];
    __shared__ float trans[64 * 130];  // [c][i], pitch 130

    const int t = threadIdx.x;
    const int blk = blockIdx.x;
    const int b = blk & 1, cc = (blk >> 1) & 3, it = blk >> 3;

    if (t < 128) {
        float sum = 0.f;
#pragma unroll
        for (int s = 0; s < 4; ++s)
            sum += ml[(size_t)((it << 3) | (s << 1) | b) * 128 + t];
        fac[t] = 1.0f / sum;
    }
    __syncthreads();

    // accumulate 4 partials (vectorized short8 loads), scale, LDS transpose
    {
        const int cgrp = t & 7, irow = t >> 3;  // 8 c-groups x 32 i-slots
#pragma unroll
        for (int ip = 0; ip < 4; ++ip) {
            int i = ip * 32 + irow;
            float a[8];
#pragma unroll
            for (int e = 0; e < 8; ++e) a[e] = 0.f;
#pragma unroll
            for (int s = 0; s < 4; ++s) {
                const unsigned short* op = Opart +
                    (size_t)((it << 3) | (s << 1) | b) * 32768 + i * 256 + cc * 64 + cgrp * 8;
                short8 o = *reinterpret_cast<const short8*>(op);
#pragma unroll
                for (int e = 0; e < 8; ++e) a[e] += bf2f((unsigned short)o[e]);
            }
            float f = fac[i];
#pragma unroll
            for (int e = 0; e < 8; ++e) trans[(cgrp * 8 + e) * 130 + i] = a[e] * f;
        }
    }
    __syncthreads();

    // coalesced residual + store
    {
        const int c2 = t >> 2, iq = t & 3;
        const int cg = cc * 64 + c2;
        const float* xr = x + (size_t)b * 2097152 + (size_t)cg * 8192 + it * 128;
        float* orow = out + (size_t)b * 2097152 + (size_t)cg * 8192 + it * 128;
#pragma unroll 2
        for (int k = 0; k < 8; ++k) {
            int i = iq * 4 + k * 16;
            float4v o;
#pragma unroll
            for (int r = 0; r < 4; ++r) o[r] = trans[c2 * 130 + i + r];
            float4v xv = *reinterpret_cast<const float4v*>(xr + i);
#pragma unroll
            for (int r = 0; r < 4; ++r) o[r] += xv[r];
            *reinterpret_cast<float4v*>(orow + i) = o;
        }
    }
}

// ---------------------------------------------------------------------------
extern "C" void kernel_launch(void* const* d_in, const int* in_sizes, int n_in,
                              void* d_out, int out_size, void* d_ws, size_t ws_size,
                              hipStream_t stream) {
    const float* x  = (const float*)d_in[0];
    const float* Wq = (const float*)d_in[1];
    const float* bq = (const float*)d_in[2];
    const float* Wk = (const float*)d_in[3];
    const float* bk = (const float*)d_in[4];
    const float* Wv = (const float*)d_in[5];
    const float* bv = (const float*)d_in[6];

    unsigned short* Whi = (unsigned short*)d_ws;           // 384*256
    unsigned short* Wlo = Whi + 384 * 256;                 // 128*256
    unsigned short* qhi = Wlo + 128 * 256;                 // [2][8192][64] blocked
    unsigned short* qlo = qhi + 2 * 8192 * 64;
    unsigned short* khi = qlo + 2 * 8192 * 64;
    unsigned short* klo = khi + 2 * 8192 * 64;
    unsigned short* vws = klo + 2 * 8192 * 64;             // [2][256][8192] blocked
    unsigned short* Opart = vws + 2 * 256 * 8192;          // 512 blk * 128 i * 256 c bf16
    float* ml = (float*)(Opart + (size_t)512 * 32768);     // 512 blk * 128

    wcvt<<<384, 256, 0, stream>>>(Wq, Wk, Wv, Whi, Wlo);
    proj<<<256, 256, 0, stream>>>(x, Whi, Wlo, bq, bk, bv, qhi, qlo, khi, klo, vws);
    attn<<<512, 256, 0, stream>>>(qhi, qlo, khi, klo, vws, Opart, ml);
    combine<<<512, 256, 0, stream>>>(Opart, ml, x, (float*)d_out);
}